// Round 10
// baseline (362.247 us; speedup 1.0000x reference)
//
#include <hip/hip_runtime.h>
#include <hip/hip_fp16.h>
#include <math.h>

#define NEG_SLOPE 0.2f
#define BN_EPS_F 1e-5f
#define NUM_G 500
#define NBUK_MAX 128
#define CHUNK 4096

typedef float v2f __attribute__((ext_vector_type(2)));

__device__ __forceinline__ float leaky(float x){ return x > 0.f ? x : NEG_SLOPE*x; }
__device__ __forceinline__ float bcast(float v, int k){
  return __int_as_float(__builtin_amdgcn_readlane(__float_as_int(v), k));
}

// ============ K1: fused bucket-hist + batch-hist + lin1-lite (att dots + x->fp8) ============
#define HB 256
#define BB 64
#define L1B 512
__global__ __launch_bounds__(256) void fused_hist_lin1_kernel(
    const int* __restrict__ edst, int E, int* __restrict__ bukcnt,
    int bshift, int nbuk,
    const int* __restrict__ batch, int* __restrict__ gcnt,
    const float* __restrict__ x, const float* __restrict__ W,
    const float* __restrict__ att_s, const float* __restrict__ att_d,
    unsigned char* __restrict__ x8, float* __restrict__ a_src, float* __restrict__ a_dst, int N)
{
  __shared__ int lhist[NUM_G];
  int t = threadIdx.x;
  int bid = blockIdx.x;
  if (bid < HB) {
    if (t < NBUK_MAX) lhist[t] = 0;
    __syncthreads();
    int i = bid*256 + t, stride = HB*256;
    for (; i < E; i += stride) atomicAdd(&lhist[edst[i] >> bshift], 1);
    __syncthreads();
    if (t < nbuk && lhist[t]) atomicAdd(&bukcnt[t], lhist[t]);
  } else if (bid < HB + BB) {
    for (int i = t; i < NUM_G; i += 256) lhist[i] = 0;
    __syncthreads();
    int i = (bid-HB)*256 + t, stride = BB*256;
    for (; i < N; i += stride) atomicAdd(&lhist[batch[i]], 1);
    __syncthreads();
    for (int i = t; i < NUM_G; i += 256) if (lhist[i]) atomicAdd(&gcnt[i], lhist[i]);
  } else {
    int lane = t & 63;
    int wid  = ((bid - HB - BB)*256 + t) >> 6;
    int nw   = (L1B*256) >> 6;
    float w[32];
    #pragma unroll
    for (int k = 0; k < 32; ++k) w[k] = W[k*64 + lane];
    float asv = att_s[lane], adv = att_d[lane];
    for (int n = wid; n < N; n += nw) {
      float xv = (lane < 32) ? x[(size_t)n*32 + lane] : 0.f;
      float acc = 0.f;
      #pragma unroll
      for (int k = 0; k < 32; ++k) acc = fmaf(bcast(xv, k), w[k], acc);
      float sv = acc*asv, dv = acc*adv;
      #pragma unroll
      for (int m = 1; m < 16; m <<= 1) { sv += __shfl_xor(sv, m); dv += __shfl_xor(dv, m); }
      // store x row as fp8 (32B)
      float xp = __shfl_xor(xv, 1);
      if (lane < 32 && (lane & 1) == 0) {
        int p = __builtin_amdgcn_cvt_pk_fp8_f32(xv, xp, 0, false);
        *(unsigned short*)(x8 + (size_t)n*32 + lane) = (unsigned short)(p & 0xffff);
      }
      if ((lane & 15) == 0) { a_src[n*4 + (lane>>4)] = sv; a_dst[n*4 + (lane>>4)] = dv; }
    }
  }
}

// ============ K2: two exclusive scans in one launch ============
__global__ __launch_bounds__(1024) void exscan2_kernel(
    const int* __restrict__ in0, int* __restrict__ out0, int n0,
    const int* __restrict__ in1, int* __restrict__ out1, int n1)
{
  const int* in  = blockIdx.x ? in1  : in0;
  int*       out = blockIdx.x ? out1 : out0;
  int        n   = blockIdx.x ? n1   : n0;
  __shared__ int part[1024];
  int t = threadIdx.x;
  int per = (n + 1023) >> 10;
  int lo = t*per, hi = lo + per; if (lo > n) lo = n; if (hi > n) hi = n;
  int s = 0;
  for (int i = lo; i < hi; ++i) s += in[i];
  part[t] = s;
  __syncthreads();
  for (int ofs = 1; ofs < 1024; ofs <<= 1) {
    int v = (t >= ofs) ? part[t-ofs] : 0;
    __syncthreads();
    part[t] += v;
    __syncthreads();
  }
  int base = part[t] - s;
  for (int i = lo; i < hi; ++i) { out[i] = base; base += in[i]; }
  if (t == 1023) out[n] = part[1023];
}

// ============ K3: binned scatter ============
__global__ __launch_bounds__(256) void binscat_kernel(
    const int* __restrict__ esrc, const int* __restrict__ edst, int E,
    const int* __restrict__ bukoff, int* __restrict__ bukcur,
    int2* __restrict__ pairs, int bshift, int nbuk)
{
  __shared__ int hist[NBUK_MAX];
  __shared__ int loffs[NBUK_MAX];
  __shared__ int gbase[NBUK_MAX];
  __shared__ int2 stage[CHUNK];
  int t = threadIdx.x;
  for (int c0 = blockIdx.x*CHUNK; c0 < E; c0 += gridDim.x*CHUNK) {
    int cnt = E - c0; if (cnt > CHUNK) cnt = CHUNK;
    if (t < NBUK_MAX) hist[t] = 0;
    __syncthreads();
    for (int i = t; i < cnt; i += 256)
      atomicAdd(&hist[edst[c0+i] >> bshift], 1);
    __syncthreads();
    int cb = (t < nbuk) ? hist[t] : 0;
    for (int ofs = 1; ofs < nbuk; ofs <<= 1) {
      int v = (t < nbuk && t >= ofs) ? hist[t-ofs] : 0;
      __syncthreads();
      if (t < nbuk) hist[t] += v;
      __syncthreads();
    }
    if (t < nbuk) {
      int lo = hist[t] - cb;
      loffs[t] = lo;
      int base = atomicAdd(&bukcur[t], cb);
      gbase[t] = bukoff[t] + base - lo;
    }
    __syncthreads();
    if (t < nbuk) hist[t] = 0;
    __syncthreads();
    for (int i = t; i < cnt; i += 256) {
      int s = esrc[c0+i], d = edst[c0+i];
      int b = d >> bshift;
      int r = atomicAdd(&hist[b], 1);
      stage[loffs[b] + r] = make_int2(s, d);
    }
    __syncthreads();
    for (int j = t; j < cnt; j += 256) {
      int2 p = stage[j];
      pairs[gbase[p.y >> bshift] + j] = p;
    }
    __syncthreads();
  }
}

// ============ K4: per-bucket CSR build ============
__global__ __launch_bounds__(512) void bucket_csr_kernel(
    const int2* __restrict__ pairs, const int* __restrict__ bukoff,
    int* __restrict__ off, int* __restrict__ csr, int N, int E, int bshift)
{
  __shared__ int cnt[1024];
  __shared__ int cur[1024];
  __shared__ int part[512];
  int b = blockIdx.x, t = threadIdx.x;
  int base = b << bshift;
  int bnodes = 1 << bshift;
  int nlocal = N - base; if (nlocal > bnodes) nlocal = bnodes;
  int lo = bukoff[b], hi = bukoff[b+1];
  int gb = lo;
  for (int i = t; i < bnodes; i += 512) cnt[i] = 0;
  __syncthreads();
  for (int i = lo + t; i < hi; i += 512) atomicAdd(&cnt[pairs[i].y - base], 1);
  __syncthreads();
  int Wc = bnodes >> 9;
  int mys = 0;
  for (int j = 0; j < Wc; ++j) mys += cnt[t*Wc + j];
  part[t] = mys;
  __syncthreads();
  for (int ofs = 1; ofs < 512; ofs <<= 1) {
    int v = (t >= ofs) ? part[t-ofs] : 0;
    __syncthreads();
    part[t] += v;
    __syncthreads();
  }
  int ex = part[t] - mys;
  for (int j = 0; j < Wc; ++j) { int c = cnt[t*Wc + j]; cnt[t*Wc + j] = ex; ex += c; }
  __syncthreads();
  for (int i = t; i < nlocal; i += 512) off[base + i] = gb + cnt[i];
  if (b == 0 && t == 0) off[N] = E;
  for (int i = t; i < bnodes; i += 512) cur[i] = 0;
  __syncthreads();
  for (int i = lo + t; i < hi; i += 512) {
    int2 p = pairs[i];
    int l = p.y - base;
    int pos = gb + cnt[l] + atomicAdd(&cur[l], 1);
    csr[pos] = p.x;
  }
}

// ============ GAT agg layer 1: gather x (fp8, 32B row, L2-resident), project in epilogue ======
// 8 edge slots x 8 lanes; lane owns 4 x-channels, accumulates all 4 heads (16 accs).
// Epilogue: agg[4][32] -> LDS, out[o] = sum_c agg[h][c]*W1[c][o], BN+ReLU -> h1 fp32 + fp8.
__global__ __launch_bounds__(256) void gat_agg1_kernel(
    const unsigned char* __restrict__ x8, const float* __restrict__ a_src, const float* __restrict__ a_dst,
    const int* __restrict__ off, const int* __restrict__ csr,
    const float* __restrict__ W1,
    const float* __restrict__ bias, const float* __restrict__ bng, const float* __restrict__ bnb,
    const float* __restrict__ bnrm, const float* __restrict__ bnrv,
    float* __restrict__ h1, unsigned char* __restrict__ h18, int N)
{
  __shared__ float W1s[32*64];        // 8KB
  __shared__ float aggs[4][4][32];    // [wave][head][ch] 2KB
  int t = threadIdx.x;
  for (int i = t; i < 32*64; i += 256) W1s[i] = W1[i];
  __syncthreads();
  int lane = t & 63;
  int wv   = t >> 6;
  int wid  = (blockIdx.x * blockDim.x + t) >> 6;
  int nw   = (gridDim.x * blockDim.x) >> 6;
  int g  = lane >> 3;        // edge slot 0..7
  int li = lane & 7;         // 8 lanes/edge
  int c0 = li * 4;           // x channels c0..c0+3
  int o  = lane;             // output channel
  int oh = o >> 4;           // output head
  float sc  = rsqrtf(bnrv[o]+BN_EPS_F) * bng[o];
  float ofc = bias[o]*sc + bnb[o] - bnrm[o]*sc;
  const float4* as4 = (const float4*)a_src;
  const float4* ad4 = (const float4*)a_dst;
  for (int n = wid; n < N; n += nw) {
    int lo = off[n], hi = off[n+1];
    float4 adn = ad4[n];
    float a0=0,a1=0,a2=0,a3=0, b0=0,b1=0,b2=0,b3=0, c1=0,c2=0,c3=0,cc0=0, d0=0,d1=0,d2=0,d3=0;
    float s0=0,s1=0,s2=0,s3=0;
    for (int e = lo; e < hi; e += 8) {
      int ee = e + g; bool ok = ee < hi;
      int idx = ok ? ee : lo;
      int s = __builtin_nontemporal_load(csr + idx);
      float4 av = as4[s];
      unsigned int rw = *(const unsigned int*)(x8 + (size_t)s*32 + c0);
      float w0 = ok ? __expf(leaky(av.x+adn.x)) : 0.f;
      float w1 = ok ? __expf(leaky(av.y+adn.y)) : 0.f;
      float w2 = ok ? __expf(leaky(av.z+adn.z)) : 0.f;
      float w3 = ok ? __expf(leaky(av.w+adn.w)) : 0.f;
      s0+=w0; s1+=w1; s2+=w2; s3+=w3;
      v2f flo = __builtin_amdgcn_cvt_pk_f32_fp8(rw, false);
      v2f fhi = __builtin_amdgcn_cvt_pk_f32_fp8(rw, true);
      a0=fmaf(w0,flo.x,a0); a1=fmaf(w0,flo.y,a1); a2=fmaf(w0,fhi.x,a2); a3=fmaf(w0,fhi.y,a3);
      b0=fmaf(w1,flo.x,b0); b1=fmaf(w1,flo.y,b1); b2=fmaf(w1,fhi.x,b2); b3=fmaf(w1,fhi.y,b3);
      cc0=fmaf(w2,flo.x,cc0); c1=fmaf(w2,flo.y,c1); c2=fmaf(w2,fhi.x,c2); c3=fmaf(w2,fhi.y,c3);
      d0=fmaf(w3,flo.x,d0); d1=fmaf(w3,flo.y,d1); d2=fmaf(w3,fhi.x,d2); d3=fmaf(w3,fhi.y,d3);
    }
    #pragma unroll
    for (int m = 8; m < 64; m <<= 1) {
      a0+=__shfl_xor(a0,m); a1+=__shfl_xor(a1,m); a2+=__shfl_xor(a2,m); a3+=__shfl_xor(a3,m);
      b0+=__shfl_xor(b0,m); b1+=__shfl_xor(b1,m); b2+=__shfl_xor(b2,m); b3+=__shfl_xor(b3,m);
      cc0+=__shfl_xor(cc0,m); c1+=__shfl_xor(c1,m); c2+=__shfl_xor(c2,m); c3+=__shfl_xor(c3,m);
      d0+=__shfl_xor(d0,m); d1+=__shfl_xor(d1,m); d2+=__shfl_xor(d2,m); d3+=__shfl_xor(d3,m);
      s0+=__shfl_xor(s0,m); s1+=__shfl_xor(s1,m); s2+=__shfl_xor(s2,m); s3+=__shfl_xor(s3,m);
    }
    // self loop (post-reduce; identical on all lanes)
    float4 asn = as4[n];
    float e0=__expf(leaky(asn.x+adn.x)), e1=__expf(leaky(asn.y+adn.y));
    float e2=__expf(leaky(asn.z+adn.z)), e3=__expf(leaky(asn.w+adn.w));
    unsigned int rw = *(const unsigned int*)(x8 + (size_t)n*32 + c0);
    v2f flo = __builtin_amdgcn_cvt_pk_f32_fp8(rw, false);
    v2f fhi = __builtin_amdgcn_cvt_pk_f32_fp8(rw, true);
    a0=fmaf(e0,flo.x,a0); a1=fmaf(e0,flo.y,a1); a2=fmaf(e0,fhi.x,a2); a3=fmaf(e0,fhi.y,a3);
    b0=fmaf(e1,flo.x,b0); b1=fmaf(e1,flo.y,b1); b2=fmaf(e1,fhi.x,b2); b3=fmaf(e1,fhi.y,b3);
    cc0=fmaf(e2,flo.x,cc0); c1=fmaf(e2,flo.y,c1); c2=fmaf(e2,fhi.x,c2); c3=fmaf(e2,fhi.y,c3);
    d0=fmaf(e3,flo.x,d0); d1=fmaf(e3,flo.y,d1); d2=fmaf(e3,fhi.x,d2); d3=fmaf(e3,fhi.y,d3);
    s0+=e0; s1+=e1; s2+=e2; s3+=e3;
    float i0=1.f/(s0+1e-16f), i1=1.f/(s1+1e-16f), i2=1.f/(s2+1e-16f), i3=1.f/(s3+1e-16f);
    if (g == 0) {   // lanes 0..7 write agg[4][32]
      aggs[wv][0][c0]=a0*i0; aggs[wv][0][c0+1]=a1*i0; aggs[wv][0][c0+2]=a2*i0; aggs[wv][0][c0+3]=a3*i0;
      aggs[wv][1][c0]=b0*i1; aggs[wv][1][c0+1]=b1*i1; aggs[wv][1][c0+2]=b2*i1; aggs[wv][1][c0+3]=b3*i1;
      aggs[wv][2][c0]=cc0*i2; aggs[wv][2][c0+1]=c1*i2; aggs[wv][2][c0+2]=c2*i2; aggs[wv][2][c0+3]=c3*i2;
      aggs[wv][3][c0]=d0*i3; aggs[wv][3][c0+1]=d1*i3; aggs[wv][3][c0+2]=d2*i3; aggs[wv][3][c0+3]=d3*i3;
    }
    // epilogue: project through W1 (in-wave LDS, no barrier needed)
    float val = 0.f;
    #pragma unroll 8
    for (int c = 0; c < 32; ++c)
      val = fmaf(aggs[wv][oh][c], W1s[c*64 + o], val);
    float r = fmaxf(fmaf(val, sc, ofc), 0.f);
    h1[(size_t)n*64 + o] = r;
    float rp = __shfl_xor(r, 1);
    if ((lane & 1) == 0) {
      int p = __builtin_amdgcn_cvt_pk_fp8_f32(r, rp, 0, false);
      *(unsigned short*)(h18 + (size_t)n*64 + o) = (unsigned short)(p & 0xffff);
    }
  }
}

// ============ lin2-lite: a_src2/a_dst2 only (no xh2 store) ============
__global__ __launch_bounds__(256) void lin2_kernel(
    const float* __restrict__ hin, const float* __restrict__ W,
    const float* __restrict__ att_s, const float* __restrict__ att_d,
    float* __restrict__ a_src, float* __restrict__ a_dst, int N)
{
  int lane = threadIdx.x & 63;
  int wid  = (blockIdx.x * blockDim.x + threadIdx.x) >> 6;
  int nw   = (gridDim.x * blockDim.x) >> 6;
  float wa[64], wb[64];
  #pragma unroll
  for (int k = 0; k < 64; ++k) { wa[k] = W[k*128 + lane]; wb[k] = W[k*128 + 64 + lane]; }
  float asa = att_s[lane], ada = att_d[lane];
  float asb = att_s[64+lane], adb = att_d[64+lane];
  for (int n = wid; n < N; n += nw) {
    float hv = hin[(size_t)n*64 + lane];
    float a0 = 0.f, a1 = 0.f;
    #pragma unroll
    for (int k = 0; k < 64; ++k) {
      float h = bcast(hv, k);
      a0 = fmaf(h, wa[k], a0); a1 = fmaf(h, wb[k], a1);
    }
    float sva = a0*asa, dva = a0*ada, svb = a1*asb, dvb = a1*adb;
    #pragma unroll
    for (int m = 1; m < 32; m <<= 1) {
      sva += __shfl_xor(sva, m); dva += __shfl_xor(dva, m);
      svb += __shfl_xor(svb, m); dvb += __shfl_xor(dvb, m);
    }
    if ((lane & 31) == 0) {
      int hh = lane >> 5;
      a_src[n*4 + hh] = sva;     a_dst[n*4 + hh] = dva;
      a_src[n*4 + 2 + hh] = svb; a_dst[n*4 + 2 + hh] = dvb;
    }
  }
}

// ============ GAT agg layer 2: gather h1 (fp8, 64B row, L2-resident), project via W2 ==========
// 4 edge slots x 16 lanes; lane owns 4 h1-channels, all 4 heads (16 accs).
// Epilogue: agg[4][64] -> LDS, out[o]=sum_c agg[h][c]*W2[c][o] (2 outputs/lane), BN+ReLU+gate.
__global__ __launch_bounds__(256) void gat_agg2_kernel(
    const unsigned char* __restrict__ h18, const float* __restrict__ a_src, const float* __restrict__ a_dst,
    const int* __restrict__ off, const int* __restrict__ csr,
    const float* __restrict__ W2,
    const float* __restrict__ bias, const float* __restrict__ bng, const float* __restrict__ bnb,
    const float* __restrict__ bnrm, const float* __restrict__ bnrv,
    const float* __restrict__ gateW, const float* __restrict__ gateB,
    float* __restrict__ hout, float* __restrict__ gate, int N)
{
  __shared__ float W2s[64*128];       // 32KB
  __shared__ float aggs[4][4][64];    // [wave][head][ch] 4KB
  int t = threadIdx.x;
  for (int i = t; i < 64*128; i += 256) W2s[i] = W2[i];
  __syncthreads();
  int lane = t & 63;
  int wv   = t >> 6;
  int wid  = (blockIdx.x * blockDim.x + t) >> 6;
  int nw   = (gridDim.x * blockDim.x) >> 6;
  int g  = lane >> 4;        // edge slot 0..3
  int li = lane & 15;        // 16 lanes/edge
  int c0 = li * 4;           // h1 channels c0..c0+3
  int o1 = lane, o2 = lane + 64;        // output channels
  int h1o = o1 >> 5, h2o = o2 >> 5;     // output heads
  float sc1  = rsqrtf(bnrv[o1]+BN_EPS_F) * bng[o1];
  float of1  = bias[o1]*sc1 + bnb[o1] - bnrm[o1]*sc1;
  float sc2  = rsqrtf(bnrv[o2]+BN_EPS_F) * bng[o2];
  float of2  = bias[o2]*sc2 + bnb[o2] - bnrm[o2]*sc2;
  float gw1 = gateW[o1], gw2 = gateW[o2], gb = gateB[0];
  const float4* as4 = (const float4*)a_src;
  const float4* ad4 = (const float4*)a_dst;
  for (int n = wid; n < N; n += nw) {
    int lo = off[n], hi = off[n+1];
    float4 adn = ad4[n];
    float a0=0,a1=0,a2=0,a3=0, b0=0,b1=0,b2=0,b3=0, cc0=0,c1=0,c2=0,c3=0, d0=0,d1=0,d2=0,d3=0;
    float s0=0,s1=0,s2=0,s3=0;
    for (int e = lo; e < hi; e += 4) {
      int ee = e + g; bool ok = ee < hi;
      int idx = ok ? ee : lo;
      int s = __builtin_nontemporal_load(csr + idx);
      float4 av = as4[s];
      unsigned int rw = *(const unsigned int*)(h18 + (size_t)s*64 + c0);
      float w0 = ok ? __expf(leaky(av.x+adn.x)) : 0.f;
      float w1 = ok ? __expf(leaky(av.y+adn.y)) : 0.f;
      float w2 = ok ? __expf(leaky(av.z+adn.z)) : 0.f;
      float w3 = ok ? __expf(leaky(av.w+adn.w)) : 0.f;
      s0+=w0; s1+=w1; s2+=w2; s3+=w3;
      v2f flo = __builtin_amdgcn_cvt_pk_f32_fp8(rw, false);
      v2f fhi = __builtin_amdgcn_cvt_pk_f32_fp8(rw, true);
      a0=fmaf(w0,flo.x,a0); a1=fmaf(w0,flo.y,a1); a2=fmaf(w0,fhi.x,a2); a3=fmaf(w0,fhi.y,a3);
      b0=fmaf(w1,flo.x,b0); b1=fmaf(w1,flo.y,b1); b2=fmaf(w1,fhi.x,b2); b3=fmaf(w1,fhi.y,b3);
      cc0=fmaf(w2,flo.x,cc0); c1=fmaf(w2,flo.y,c1); c2=fmaf(w2,fhi.x,c2); c3=fmaf(w2,fhi.y,c3);
      d0=fmaf(w3,flo.x,d0); d1=fmaf(w3,flo.y,d1); d2=fmaf(w3,fhi.x,d2); d3=fmaf(w3,fhi.y,d3);
    }
    #pragma unroll
    for (int m = 16; m < 64; m <<= 1) {
      a0+=__shfl_xor(a0,m); a1+=__shfl_xor(a1,m); a2+=__shfl_xor(a2,m); a3+=__shfl_xor(a3,m);
      b0+=__shfl_xor(b0,m); b1+=__shfl_xor(b1,m); b2+=__shfl_xor(b2,m); b3+=__shfl_xor(b3,m);
      cc0+=__shfl_xor(cc0,m); c1+=__shfl_xor(c1,m); c2+=__shfl_xor(c2,m); c3+=__shfl_xor(c3,m);
      d0+=__shfl_xor(d0,m); d1+=__shfl_xor(d1,m); d2+=__shfl_xor(d2,m); d3+=__shfl_xor(d3,m);
      s0+=__shfl_xor(s0,m); s1+=__shfl_xor(s1,m); s2+=__shfl_xor(s2,m); s3+=__shfl_xor(s3,m);
    }
    float4 asn = as4[n];
    float e0=__expf(leaky(asn.x+adn.x)), e1=__expf(leaky(asn.y+adn.y));
    float e2=__expf(leaky(asn.z+adn.z)), e3=__expf(leaky(asn.w+adn.w));
    unsigned int rw = *(const unsigned int*)(h18 + (size_t)n*64 + c0);
    v2f flo = __builtin_amdgcn_cvt_pk_f32_fp8(rw, false);
    v2f fhi = __builtin_amdgcn_cvt_pk_f32_fp8(rw, true);
    a0=fmaf(e0,flo.x,a0); a1=fmaf(e0,flo.y,a1); a2=fmaf(e0,fhi.x,a2); a3=fmaf(e0,fhi.y,a3);
    b0=fmaf(e1,flo.x,b0); b1=fmaf(e1,flo.y,b1); b2=fmaf(e1,fhi.x,b2); b3=fmaf(e1,fhi.y,b3);
    cc0=fmaf(e2,flo.x,cc0); c1=fmaf(e2,flo.y,c1); c2=fmaf(e2,fhi.x,c2); c3=fmaf(e2,fhi.y,c3);
    d0=fmaf(e3,flo.x,d0); d1=fmaf(e3,flo.y,d1); d2=fmaf(e3,fhi.x,d2); d3=fmaf(e3,fhi.y,d3);
    s0+=e0; s1+=e1; s2+=e2; s3+=e3;
    float i0=1.f/(s0+1e-16f), i1=1.f/(s1+1e-16f), i2=1.f/(s2+1e-16f), i3=1.f/(s3+1e-16f);
    if (g == 0) {   // lanes 0..15 write agg[4][64]
      aggs[wv][0][c0]=a0*i0; aggs[wv][0][c0+1]=a1*i0; aggs[wv][0][c0+2]=a2*i0; aggs[wv][0][c0+3]=a3*i0;
      aggs[wv][1][c0]=b0*i1; aggs[wv][1][c0+1]=b1*i1; aggs[wv][1][c0+2]=b2*i1; aggs[wv][1][c0+3]=b3*i1;
      aggs[wv][2][c0]=cc0*i2; aggs[wv][2][c0+1]=c1*i2; aggs[wv][2][c0+2]=c2*i2; aggs[wv][2][c0+3]=c3*i2;
      aggs[wv][3][c0]=d0*i3; aggs[wv][3][c0+1]=d1*i3; aggs[wv][3][c0+2]=d2*i3; aggs[wv][3][c0+3]=d3*i3;
    }
    // epilogue: project through W2 (in-wave LDS)
    float v1 = 0.f, v2 = 0.f;
    #pragma unroll 8
    for (int c = 0; c < 64; ++c) {
      v1 = fmaf(aggs[wv][h1o][c], W2s[c*128 + o1], v1);
      v2 = fmaf(aggs[wv][h2o][c], W2s[c*128 + o2], v2);
    }
    float r1 = fmaxf(fmaf(v1, sc1, of1), 0.f);
    float r2 = fmaxf(fmaf(v2, sc2, of2), 0.f);
    hout[(size_t)n*128 + o1] = r1;
    hout[(size_t)n*128 + o2] = r2;
    float gl = r1*gw1 + r2*gw2;
    #pragma unroll
    for (int m = 1; m < 64; m <<= 1) gl += __shfl_xor(gl, m);
    if (lane == 0) gate[n] = gl + gb;
  }
}

// ============ per-graph attention pooling + MLP heads ============
__global__ __launch_bounds__(128) void pool_kernel(
    const float* __restrict__ h2, const float* __restrict__ gate, const int* __restrict__ goff,
    const float* __restrict__ fc1W, const float* __restrict__ fc1b,
    const float* __restrict__ valW, const float* __restrict__ valb,
    const float* __restrict__ advW, const float* __restrict__ advb,
    float* __restrict__ out)
{
  int g = blockIdx.x, t = threadIdx.x;
  int lo = goff[g], hi = goff[g+1];
  __shared__ float red[2];
  __shared__ float pld[128];
  __shared__ float zs[32];
  __shared__ float sval;
  __shared__ float adv_s[16];

  float m = -3.4e38f;
  for (int n = lo+t; n < hi; n += 128) m = fmaxf(m, gate[n]);
  #pragma unroll
  for (int msk = 1; msk < 64; msk <<= 1) m = fmaxf(m, __shfl_xor(m, msk));
  if ((t & 63) == 0) red[t >> 6] = m;
  __syncthreads();
  m = fmaxf(red[0], red[1]);
  __syncthreads();
  float sl = 0.f;
  for (int n = lo+t; n < hi; n += 128) sl += __expf(gate[n]-m);
  #pragma unroll
  for (int msk = 1; msk < 64; msk <<= 1) sl += __shfl_xor(sl, msk);
  if ((t & 63) == 0) red[t >> 6] = sl;
  __syncthreads();
  float s = red[0] + red[1];
  float acc = 0.f;
  for (int n = lo; n < hi; ++n) {
    float w = __expf(gate[n]-m);
    acc += w * h2[(size_t)n*128 + t];
  }
  pld[t] = acc / (s + 1e-16f);
  __syncthreads();
  if (t < 32) {
    float z = fc1b[t];
    #pragma unroll 4
    for (int k = 0; k < 128; ++k) z += pld[k]*fc1W[k*32 + t];
    zs[t] = fmaxf(z, 0.f);
  }
  __syncthreads();
  if (t < 32) {
    float pv = zs[t]*valW[t];
    #pragma unroll
    for (int msk = 1; msk < 32; msk <<= 1) pv += __shfl_xor(pv, msk);
    if (t == 0) sval = pv + valb[0];
  }
  if (t < 16) {
    float a = advb[t];
    #pragma unroll
    for (int k = 0; k < 32; ++k) a += zs[k]*advW[k*16 + t];
    adv_s[t] = a;
  }
  __syncthreads();
  if (t < 16) {
    float amean = adv_s[t];
    #pragma unroll
    for (int msk = 1; msk < 16; msk <<= 1) amean += __shfl_xor(amean, msk);
    amean *= (1.f/16.f);
    out[g*16 + t] = sval + adv_s[t] - amean;
  }
}

extern "C" void kernel_launch(void* const* d_in, const int* in_sizes, int n_in,
                              void* d_out, int out_size, void* d_ws, size_t ws_size,
                              hipStream_t stream)
{
  const float* x     = (const float*)d_in[0];
  const int*   eidx  = (const int*)  d_in[1];
  const int*   batch = (const int*)  d_in[2];
  const float* W1    = (const float*)d_in[3];
  const float* as1w  = (const float*)d_in[4];
  const float* ad1w  = (const float*)d_in[5];
  const float* b1    = (const float*)d_in[6];
  const float* bn1g  = (const float*)d_in[7];
  const float* bn1b  = (const float*)d_in[8];
  const float* bn1rm = (const float*)d_in[9];
  const float* bn1rv = (const float*)d_in[10];
  const float* W2    = (const float*)d_in[11];
  const float* as2w  = (const float*)d_in[12];
  const float* ad2w  = (const float*)d_in[13];
  const float* b2    = (const float*)d_in[14];
  const float* bn2g  = (const float*)d_in[15];
  const float* bn2b  = (const float*)d_in[16];
  const float* bn2rm = (const float*)d_in[17];
  const float* bn2rv = (const float*)d_in[18];
  const float* gateW = (const float*)d_in[19];
  const float* gateB = (const float*)d_in[20];
  const float* fc1W  = (const float*)d_in[21];
  const float* fc1b  = (const float*)d_in[22];
  const float* valW  = (const float*)d_in[23];
  const float* valb  = (const float*)d_in[24];
  const float* advW  = (const float*)d_in[25];
  const float* advb  = (const float*)d_in[26];

  int N = in_sizes[0] / 32;
  int E = in_sizes[1] / 2;
  const int* esrc = eidx;
  const int* edst = eidx + E;

  int bshift = 9;
  while ((((N - 1) >> bshift) + 1) > NBUK_MAX) ++bshift;
  int nbuk = ((N - 1) >> bshift) + 1;

  float* ws = (float*)d_ws;
  size_t o = 0;
  unsigned char* x8  = (unsigned char*)(ws + o); o += (size_t)N*8;    // N*32 fp8 bytes
  unsigned char* h18 = (unsigned char*)(ws + o); o += (size_t)N*16;   // N*64 fp8 bytes
  float* as1 = ws + o; o += (size_t)N*4;
  float* ad1 = ws + o; o += (size_t)N*4;
  float* as2 = ws + o; o += (size_t)N*4;
  float* ad2 = ws + o; o += (size_t)N*4;
  float* h1  = ws + o; o += (size_t)N*64;
  float* h2  = ws + o; o += (size_t)N*128;
  float* gate = ws + o; o += (size_t)N;
  if (o & 1) ++o;
  int2* pairs = (int2*)(ws + o); o += (size_t)E*2;
  int* ib     = (int*)(ws + o);
  int* gcnt   = ib;
  int* bukcnt = ib + 512;
  int* bukcur = ib + 640;
  size_t zcnt = 768;
  int* off    = ib + zcnt;                 // N+1
  int* goff   = off + (N+1);               // NUM_G+1
  int* bukoff = goff + (NUM_G+1);          // nbuk+1
  int* csr    = bukoff + (NBUK_MAX+1);     // E

  hipMemsetAsync(gcnt, 0, zcnt*sizeof(int), stream);

  fused_hist_lin1_kernel<<<HB+BB+L1B, 256, 0, stream>>>(
      edst, E, bukcnt, bshift, nbuk, batch, gcnt,
      x, W1, as1w, ad1w, x8, as1, ad1, N);
  exscan2_kernel<<<2, 1024, 0, stream>>>(bukcnt, bukoff, nbuk, gcnt, goff, NUM_G);
  int nchunk = (E + CHUNK - 1) / CHUNK;
  binscat_kernel<<<nchunk, 256, 0, stream>>>(esrc, edst, E, bukoff, bukcur, pairs, bshift, nbuk);
  bucket_csr_kernel<<<nbuk, 512, 0, stream>>>(pairs, bukoff, off, csr, N, E, bshift);
  gat_agg1_kernel<<<2048, 256, 0, stream>>>(x8, as1, ad1, off, csr, W1,
      b1, bn1g, bn1b, bn1rm, bn1rv, h1, h18, N);
  lin2_kernel<<<1024, 256, 0, stream>>>(h1, W2, as2w, ad2w, as2, ad2, N);
  gat_agg2_kernel<<<2048, 256, 0, stream>>>(h18, as2, ad2, off, csr, W2,
      b2, bn2g, bn2b, bn2rm, bn2rv, gateW, gateB, h2, gate, N);
  pool_kernel<<<NUM_G, 128, 0, stream>>>(h2, gate, goff, fc1W, fc1b, valW, valb, advW, advb,
      (float*)d_out);
}

// Round 11
// 246.594 us; speedup vs baseline: 1.4690x; 1.4690x over previous
//
#include <hip/hip_runtime.h>
#include <hip/hip_fp16.h>
#include <math.h>

#define NEG_SLOPE 0.2f
#define BN_EPS_F 1e-5f
#define NUM_G 500
#define NBUK_MAX 128
#define CHUNK 4096

__device__ __forceinline__ float leaky(float x){ return x > 0.f ? x : NEG_SLOPE*x; }
__device__ __forceinline__ float bcast(float v, int k){
  return __int_as_float(__builtin_amdgcn_readlane(__float_as_int(v), k));
}

// ============ K1: fused bucket-hist + batch-hist + lin1 (role split by blockIdx) ============
#define HB 256
#define BB 64
#define L1B 512
__global__ __launch_bounds__(256) void fused_hist_lin1_kernel(
    const int* __restrict__ edst, int E, int* __restrict__ bukcnt,
    int bshift, int nbuk,
    const int* __restrict__ batch, int* __restrict__ gcnt,
    const float* __restrict__ x, const float* __restrict__ W,
    const float* __restrict__ att_s, const float* __restrict__ att_d,
    __half* __restrict__ xh, float* __restrict__ a_src, float* __restrict__ a_dst, int N)
{
  __shared__ int lhist[NUM_G];
  int t = threadIdx.x;
  int bid = blockIdx.x;
  if (bid < HB) {
    if (t < NBUK_MAX) lhist[t] = 0;
    __syncthreads();
    int i = bid*256 + t, stride = HB*256;
    for (; i < E; i += stride) atomicAdd(&lhist[edst[i] >> bshift], 1);
    __syncthreads();
    if (t < nbuk && lhist[t]) atomicAdd(&bukcnt[t], lhist[t]);
  } else if (bid < HB + BB) {
    for (int i = t; i < NUM_G; i += 256) lhist[i] = 0;
    __syncthreads();
    int i = (bid-HB)*256 + t, stride = BB*256;
    for (; i < N; i += stride) atomicAdd(&lhist[batch[i]], 1);
    __syncthreads();
    for (int i = t; i < NUM_G; i += 256) if (lhist[i]) atomicAdd(&gcnt[i], lhist[i]);
  } else {
    int lane = t & 63;
    int wid  = ((bid - HB - BB)*256 + t) >> 6;
    int nw   = (L1B*256) >> 6;
    float w[32];
    #pragma unroll
    for (int k = 0; k < 32; ++k) w[k] = W[k*64 + lane];
    float asv = att_s[lane], adv = att_d[lane];
    for (int n = wid; n < N; n += nw) {
      float xv = (lane < 32) ? x[(size_t)n*32 + lane] : 0.f;
      float acc = 0.f;
      #pragma unroll
      for (int k = 0; k < 32; ++k) acc = fmaf(bcast(xv, k), w[k], acc);
      float sv = acc*asv, dv = acc*adv;
      #pragma unroll
      for (int m = 1; m < 16; m <<= 1) { sv += __shfl_xor(sv, m); dv += __shfl_xor(dv, m); }
      xh[(size_t)n*64 + lane] = __float2half(acc);
      if ((lane & 15) == 0) { a_src[n*4 + (lane>>4)] = sv; a_dst[n*4 + (lane>>4)] = dv; }
    }
  }
}

// ============ K2: two exclusive scans in one launch ============
__global__ __launch_bounds__(1024) void exscan2_kernel(
    const int* __restrict__ in0, int* __restrict__ out0, int n0,
    const int* __restrict__ in1, int* __restrict__ out1, int n1)
{
  const int* in  = blockIdx.x ? in1  : in0;
  int*       out = blockIdx.x ? out1 : out0;
  int        n   = blockIdx.x ? n1   : n0;
  __shared__ int part[1024];
  int t = threadIdx.x;
  int per = (n + 1023) >> 10;
  int lo = t*per, hi = lo + per; if (lo > n) lo = n; if (hi > n) hi = n;
  int s = 0;
  for (int i = lo; i < hi; ++i) s += in[i];
  part[t] = s;
  __syncthreads();
  for (int ofs = 1; ofs < 1024; ofs <<= 1) {
    int v = (t >= ofs) ? part[t-ofs] : 0;
    __syncthreads();
    part[t] += v;
    __syncthreads();
  }
  int base = part[t] - s;
  for (int i = lo; i < hi; ++i) { out[i] = base; base += in[i]; }
  if (t == 1023) out[n] = part[1023];
}

// ============ K3: binned scatter ============
__global__ __launch_bounds__(256) void binscat_kernel(
    const int* __restrict__ esrc, const int* __restrict__ edst, int E,
    const int* __restrict__ bukoff, int* __restrict__ bukcur,
    int2* __restrict__ pairs, int bshift, int nbuk)
{
  __shared__ int hist[NBUK_MAX];
  __shared__ int loffs[NBUK_MAX];
  __shared__ int gbase[NBUK_MAX];
  __shared__ int2 stage[CHUNK];
  int t = threadIdx.x;
  for (int c0 = blockIdx.x*CHUNK; c0 < E; c0 += gridDim.x*CHUNK) {
    int cnt = E - c0; if (cnt > CHUNK) cnt = CHUNK;
    if (t < NBUK_MAX) hist[t] = 0;
    __syncthreads();
    for (int i = t; i < cnt; i += 256)
      atomicAdd(&hist[edst[c0+i] >> bshift], 1);
    __syncthreads();
    int cb = (t < nbuk) ? hist[t] : 0;
    for (int ofs = 1; ofs < nbuk; ofs <<= 1) {
      int v = (t < nbuk && t >= ofs) ? hist[t-ofs] : 0;
      __syncthreads();
      if (t < nbuk) hist[t] += v;
      __syncthreads();
    }
    if (t < nbuk) {
      int lo = hist[t] - cb;
      loffs[t] = lo;
      int base = atomicAdd(&bukcur[t], cb);
      gbase[t] = bukoff[t] + base - lo;
    }
    __syncthreads();
    if (t < nbuk) hist[t] = 0;
    __syncthreads();
    for (int i = t; i < cnt; i += 256) {
      int s = esrc[c0+i], d = edst[c0+i];
      int b = d >> bshift;
      int r = atomicAdd(&hist[b], 1);
      stage[loffs[b] + r] = make_int2(s, d);
    }
    __syncthreads();
    for (int j = t; j < cnt; j += 256) {
      int2 p = stage[j];
      pairs[gbase[p.y >> bshift] + j] = p;
    }
    __syncthreads();
  }
}

// ============ K4: per-bucket CSR build ============
__global__ __launch_bounds__(512) void bucket_csr_kernel(
    const int2* __restrict__ pairs, const int* __restrict__ bukoff,
    int* __restrict__ off, int* __restrict__ csr, int N, int E, int bshift)
{
  __shared__ int cnt[1024];
  __shared__ int cur[1024];
  __shared__ int part[512];
  int b = blockIdx.x, t = threadIdx.x;
  int base = b << bshift;
  int bnodes = 1 << bshift;
  int nlocal = N - base; if (nlocal > bnodes) nlocal = bnodes;
  int lo = bukoff[b], hi = bukoff[b+1];
  int gb = lo;
  for (int i = t; i < bnodes; i += 512) cnt[i] = 0;
  __syncthreads();
  for (int i = lo + t; i < hi; i += 512) atomicAdd(&cnt[pairs[i].y - base], 1);
  __syncthreads();
  int Wc = bnodes >> 9;
  int mys = 0;
  for (int j = 0; j < Wc; ++j) mys += cnt[t*Wc + j];
  part[t] = mys;
  __syncthreads();
  for (int ofs = 1; ofs < 512; ofs <<= 1) {
    int v = (t >= ofs) ? part[t-ofs] : 0;
    __syncthreads();
    part[t] += v;
    __syncthreads();
  }
  int ex = part[t] - mys;
  for (int j = 0; j < Wc; ++j) { int c = cnt[t*Wc + j]; cnt[t*Wc + j] = ex; ex += c; }
  __syncthreads();
  for (int i = t; i < nlocal; i += 512) off[base + i] = gb + cnt[i];
  if (b == 0 && t == 0) off[N] = E;
  for (int i = t; i < bnodes; i += 512) cur[i] = 0;
  __syncthreads();
  for (int i = lo + t; i < hi; i += 512) {
    int2 p = pairs[i];
    int l = p.y - base;
    int pos = gb + cnt[l] + atomicAdd(&cur[l], 1);
    csr[pos] = p.x;
  }
}

// ============ GAT agg layer 1 (F=64): 8 edges/iter (2x unroll), 16 lanes/edge, 4ch/lane ====
// (R7 variant: measured best for agg1)
__global__ __launch_bounds__(256) void gat_agg1_kernel(
    const __half* __restrict__ xh, const float* __restrict__ a_src, const float* __restrict__ a_dst,
    const int* __restrict__ off, const int* __restrict__ csr,
    const float* __restrict__ bias, const float* __restrict__ bng, const float* __restrict__ bnb,
    const float* __restrict__ bnrm, const float* __restrict__ bnrv,
    float* __restrict__ hout, int N)
{
  int lane = threadIdx.x & 63;
  int wid  = (blockIdx.x * blockDim.x + threadIdx.x) >> 6;
  int nw   = (gridDim.x * blockDim.x) >> 6;
  int g  = lane >> 4;
  int li = lane & 15;
  int c0 = li * 4;
  int h  = li >> 2;
  float sc[4], of[4];
  #pragma unroll
  for (int j = 0; j < 4; ++j) {
    sc[j] = rsqrtf(bnrv[c0+j]+BN_EPS_F) * bng[c0+j];
    of[j] = bias[c0+j]*sc[j] + bnb[c0+j] - bnrm[c0+j]*sc[j];
  }
  for (int n = wid; n < N; n += nw) {
    int lo = off[n], hi = off[n+1];
    float adh = a_dst[n*4+h];
    float es  = __expf(leaky(a_src[n*4+h] + adh));
    float acc0=0.f, acc1=0.f, acc2=0.f, acc3=0.f, ssum=0.f;
    for (int e = lo; e < hi; e += 8) {
      int ee0 = e + g, ee1 = e + 4 + g;
      bool ok0 = ee0 < hi, ok1 = ee1 < hi;
      int s0 = csr[ok0 ? ee0 : lo];
      int s1 = csr[ok1 ? ee1 : lo];
      float a0 = a_src[s0*4+h];
      float a1 = a_src[s1*4+h];
      int2 rv0 = *(const int2*)(xh + (size_t)s0*64 + c0);
      int2 rv1 = *(const int2*)(xh + (size_t)s1*64 + c0);
      float w0 = ok0 ? __expf(leaky(a0+adh)) : 0.f;
      float w1 = ok1 ? __expf(leaky(a1+adh)) : 0.f;
      ssum += w0 + w1;
      float2 p0 = __half22float2(*(__half2*)&rv0.x);
      float2 p1 = __half22float2(*(__half2*)&rv0.y);
      float2 q0 = __half22float2(*(__half2*)&rv1.x);
      float2 q1 = __half22float2(*(__half2*)&rv1.y);
      acc0 = fmaf(w0, p0.x, acc0); acc1 = fmaf(w0, p0.y, acc1);
      acc2 = fmaf(w0, p1.x, acc2); acc3 = fmaf(w0, p1.y, acc3);
      acc0 = fmaf(w1, q0.x, acc0); acc1 = fmaf(w1, q0.y, acc1);
      acc2 = fmaf(w1, q1.x, acc2); acc3 = fmaf(w1, q1.y, acc3);
    }
    #pragma unroll
    for (int m = 16; m < 64; m <<= 1) {
      acc0 += __shfl_xor(acc0, m); acc1 += __shfl_xor(acc1, m);
      acc2 += __shfl_xor(acc2, m); acc3 += __shfl_xor(acc3, m);
      ssum += __shfl_xor(ssum, m);
    }
    int2 rv = *(const int2*)(xh + (size_t)n*64 + c0);
    float2 f0 = __half22float2(*(__half2*)&rv.x);
    float2 f1 = __half22float2(*(__half2*)&rv.y);
    acc0 = fmaf(es, f0.x, acc0); acc1 = fmaf(es, f0.y, acc1);
    acc2 = fmaf(es, f1.x, acc2); acc3 = fmaf(es, f1.y, acc3);
    ssum += es;
    float inv = 1.f / (ssum + 1e-16f);
    if (g == 0) {
      float4 r;
      r.x = fmaxf(fmaf(acc0*inv, sc[0], of[0]), 0.f);
      r.y = fmaxf(fmaf(acc1*inv, sc[1], of[1]), 0.f);
      r.z = fmaxf(fmaf(acc2*inv, sc[2], of[2]), 0.f);
      r.w = fmaxf(fmaf(acc3*inv, sc[3], of[3]), 0.f);
      *(float4*)(hout + (size_t)n*64 + c0) = r;
    }
  }
}

// ============ linear 2 ============
__global__ __launch_bounds__(256) void lin2_kernel(
    const float* __restrict__ hin, const float* __restrict__ W,
    const float* __restrict__ att_s, const float* __restrict__ att_d,
    __half* __restrict__ xh, float* __restrict__ a_src, float* __restrict__ a_dst, int N)
{
  int lane = threadIdx.x & 63;
  int wid  = (blockIdx.x * blockDim.x + threadIdx.x) >> 6;
  int nw   = (gridDim.x * blockDim.x) >> 6;
  float wa[64], wb[64];
  #pragma unroll
  for (int k = 0; k < 64; ++k) { wa[k] = W[k*128 + lane]; wb[k] = W[k*128 + 64 + lane]; }
  float asa = att_s[lane], ada = att_d[lane];
  float asb = att_s[64+lane], adb = att_d[64+lane];
  for (int n = wid; n < N; n += nw) {
    float hv = hin[(size_t)n*64 + lane];
    float a0 = 0.f, a1 = 0.f;
    #pragma unroll
    for (int k = 0; k < 64; ++k) {
      float h = bcast(hv, k);
      a0 = fmaf(h, wa[k], a0); a1 = fmaf(h, wb[k], a1);
    }
    float sva = a0*asa, dva = a0*ada, svb = a1*asb, dvb = a1*adb;
    #pragma unroll
    for (int m = 1; m < 32; m <<= 1) {
      sva += __shfl_xor(sva, m); dva += __shfl_xor(dva, m);
      svb += __shfl_xor(svb, m); dvb += __shfl_xor(dvb, m);
    }
    xh[(size_t)n*128 + lane] = __float2half(a0);
    xh[(size_t)n*128 + 64 + lane] = __float2half(a1);
    if ((lane & 31) == 0) {
      int hh = lane >> 5;
      a_src[n*4 + hh] = sva;     a_dst[n*4 + hh] = dva;
      a_src[n*4 + 2 + hh] = svb; a_dst[n*4 + 2 + hh] = dvb;
    }
  }
}

// ============ GAT agg layer 2 (F=128): 4 edges/iter, 16 lanes/edge, 8ch/lane ============
// (R6 variant: measured best for agg2)
__global__ __launch_bounds__(256) void gat_agg2_kernel(
    const __half* __restrict__ xh, const float* __restrict__ a_src, const float* __restrict__ a_dst,
    const int* __restrict__ off, const int* __restrict__ csr,
    const float* __restrict__ bias, const float* __restrict__ bng, const float* __restrict__ bnb,
    const float* __restrict__ bnrm, const float* __restrict__ bnrv,
    const float* __restrict__ gateW, const float* __restrict__ gateB,
    float* __restrict__ hout, float* __restrict__ gate, int N)
{
  int lane = threadIdx.x & 63;
  int wid  = (blockIdx.x * blockDim.x + threadIdx.x) >> 6;
  int nw   = (gridDim.x * blockDim.x) >> 6;
  int g  = lane >> 4;        // edge slot 0..3
  int li = lane & 15;        // 16 lanes per edge
  int c0 = li * 8;           // channels c0..c0+7
  int h  = li >> 2;          // head = c0>>5
  float sc[8], of[8], gw[8];
  #pragma unroll
  for (int j = 0; j < 8; ++j) {
    sc[j] = rsqrtf(bnrv[c0+j]+BN_EPS_F) * bng[c0+j];
    of[j] = bias[c0+j]*sc[j] + bnb[c0+j] - bnrm[c0+j]*sc[j];
    gw[j] = gateW[c0+j];
  }
  float gb = gateB[0];
  for (int n = wid; n < N; n += nw) {
    int lo = off[n], hi = off[n+1];
    float adh = a_dst[n*4+h];
    float es  = __expf(leaky(a_src[n*4+h] + adh));
    float acc0=0.f, acc1=0.f, acc2=0.f, acc3=0.f;
    float acc4=0.f, acc5=0.f, acc6=0.f, acc7=0.f, ssum=0.f;
    for (int e = lo; e < hi; e += 4) {
      int ee = e + g; bool ok = ee < hi;
      int s = csr[ok ? ee : lo];
      float a = a_src[s*4+h];
      int4 rv = *(const int4*)(xh + (size_t)s*128 + c0);
      float w = ok ? __expf(leaky(a+adh)) : 0.f;
      ssum += w;
      float2 f0 = __half22float2(*(__half2*)&rv.x);
      float2 f1 = __half22float2(*(__half2*)&rv.y);
      float2 f2 = __half22float2(*(__half2*)&rv.z);
      float2 f3 = __half22float2(*(__half2*)&rv.w);
      acc0 = fmaf(w, f0.x, acc0); acc1 = fmaf(w, f0.y, acc1);
      acc2 = fmaf(w, f1.x, acc2); acc3 = fmaf(w, f1.y, acc3);
      acc4 = fmaf(w, f2.x, acc4); acc5 = fmaf(w, f2.y, acc5);
      acc6 = fmaf(w, f3.x, acc6); acc7 = fmaf(w, f3.y, acc7);
    }
    #pragma unroll
    for (int m = 16; m < 64; m <<= 1) {
      acc0 += __shfl_xor(acc0, m); acc1 += __shfl_xor(acc1, m);
      acc2 += __shfl_xor(acc2, m); acc3 += __shfl_xor(acc3, m);
      acc4 += __shfl_xor(acc4, m); acc5 += __shfl_xor(acc5, m);
      acc6 += __shfl_xor(acc6, m); acc7 += __shfl_xor(acc7, m);
      ssum += __shfl_xor(ssum, m);
    }
    // self loop
    int4 rv = *(const int4*)(xh + (size_t)n*128 + c0);
    float2 f0 = __half22float2(*(__half2*)&rv.x);
    float2 f1 = __half22float2(*(__half2*)&rv.y);
    float2 f2 = __half22float2(*(__half2*)&rv.z);
    float2 f3 = __half22float2(*(__half2*)&rv.w);
    acc0 = fmaf(es, f0.x, acc0); acc1 = fmaf(es, f0.y, acc1);
    acc2 = fmaf(es, f1.x, acc2); acc3 = fmaf(es, f1.y, acc3);
    acc4 = fmaf(es, f2.x, acc4); acc5 = fmaf(es, f2.y, acc5);
    acc6 = fmaf(es, f3.x, acc6); acc7 = fmaf(es, f3.y, acc7);
    ssum += es;
    float inv = 1.f / (ssum + 1e-16f);
    float r0 = fmaxf(fmaf(acc0*inv, sc[0], of[0]), 0.f);
    float r1 = fmaxf(fmaf(acc1*inv, sc[1], of[1]), 0.f);
    float r2 = fmaxf(fmaf(acc2*inv, sc[2], of[2]), 0.f);
    float r3 = fmaxf(fmaf(acc3*inv, sc[3], of[3]), 0.f);
    float r4 = fmaxf(fmaf(acc4*inv, sc[4], of[4]), 0.f);
    float r5 = fmaxf(fmaf(acc5*inv, sc[5], of[5]), 0.f);
    float r6 = fmaxf(fmaf(acc6*inv, sc[6], of[6]), 0.f);
    float r7 = fmaxf(fmaf(acc7*inv, sc[7], of[7]), 0.f);
    if (g == 0) {
      float4 w0 = make_float4(r0, r1, r2, r3);
      float4 w1 = make_float4(r4, r5, r6, r7);
      *(float4*)(hout + (size_t)n*128 + c0)     = w0;
      *(float4*)(hout + (size_t)n*128 + c0 + 4) = w1;
    }
    float gl = r0*gw[0] + r1*gw[1] + r2*gw[2] + r3*gw[3]
             + r4*gw[4] + r5*gw[5] + r6*gw[6] + r7*gw[7];
    #pragma unroll
    for (int m = 1; m < 16; m <<= 1) gl += __shfl_xor(gl, m);
    if (lane == 0) gate[n] = gl + gb;
  }
}

// ============ per-graph attention pooling + MLP heads (256 threads, 2x node parallel) ========
__global__ __launch_bounds__(256) void pool_kernel(
    const float* __restrict__ h2, const float* __restrict__ gate, const int* __restrict__ goff,
    const float* __restrict__ fc1W, const float* __restrict__ fc1b,
    const float* __restrict__ valW, const float* __restrict__ valb,
    const float* __restrict__ advW, const float* __restrict__ advb,
    float* __restrict__ out)
{
  int g = blockIdx.x, t = threadIdx.x;
  int lo = goff[g], hi = goff[g+1];
  __shared__ float red[4];
  __shared__ float pld2[2][128];
  __shared__ float pld[128];
  __shared__ float zs[32];
  __shared__ float sval;
  __shared__ float adv_s[16];

  float m = -3.4e38f;
  for (int n = lo+t; n < hi; n += 256) m = fmaxf(m, gate[n]);
  #pragma unroll
  for (int msk = 1; msk < 64; msk <<= 1) m = fmaxf(m, __shfl_xor(m, msk));
  if ((t & 63) == 0) red[t >> 6] = m;
  __syncthreads();
  m = fmaxf(fmaxf(red[0], red[1]), fmaxf(red[2], red[3]));
  __syncthreads();
  float sl = 0.f;
  for (int n = lo+t; n < hi; n += 256) sl += __expf(gate[n]-m);
  #pragma unroll
  for (int msk = 1; msk < 64; msk <<= 1) sl += __shfl_xor(sl, msk);
  if ((t & 63) == 0) red[t >> 6] = sl;
  __syncthreads();
  float s = red[0] + red[1] + red[2] + red[3];
  // weighted sum: feature f, node parity p
  int f = t & 127, p = t >> 7;
  float acc = 0.f;
  for (int n = lo + p; n < hi; n += 2) {
    float w = __expf(gate[n]-m);
    acc += w * h2[(size_t)n*128 + f];
  }
  pld2[p][f] = acc;
  __syncthreads();
  if (t < 128) pld[t] = (pld2[0][t] + pld2[1][t]) / (s + 1e-16f);
  __syncthreads();
  if (t < 32) {
    float z = fc1b[t];
    #pragma unroll 4
    for (int k = 0; k < 128; ++k) z += pld[k]*fc1W[k*32 + t];
    zs[t] = fmaxf(z, 0.f);
  }
  __syncthreads();
  if (t < 32) {
    float pv = zs[t]*valW[t];
    #pragma unroll
    for (int msk = 1; msk < 32; msk <<= 1) pv += __shfl_xor(pv, msk);
    if (t == 0) sval = pv + valb[0];
  }
  if (t < 16) {
    float a = advb[t];
    #pragma unroll
    for (int k = 0; k < 32; ++k) a += zs[k]*advW[k*16 + t];
    adv_s[t] = a;
  }
  __syncthreads();
  if (t < 16) {
    float amean = adv_s[t];
    #pragma unroll
    for (int msk = 1; msk < 16; msk <<= 1) amean += __shfl_xor(amean, msk);
    amean *= (1.f/16.f);
    out[g*16 + t] = sval + adv_s[t] - amean;
  }
}

extern "C" void kernel_launch(void* const* d_in, const int* in_sizes, int n_in,
                              void* d_out, int out_size, void* d_ws, size_t ws_size,
                              hipStream_t stream)
{
  const float* x     = (const float*)d_in[0];
  const int*   eidx  = (const int*)  d_in[1];
  const int*   batch = (const int*)  d_in[2];
  const float* W1    = (const float*)d_in[3];
  const float* as1w  = (const float*)d_in[4];
  const float* ad1w  = (const float*)d_in[5];
  const float* b1    = (const float*)d_in[6];
  const float* bn1g  = (const float*)d_in[7];
  const float* bn1b  = (const float*)d_in[8];
  const float* bn1rm = (const float*)d_in[9];
  const float* bn1rv = (const float*)d_in[10];
  const float* W2    = (const float*)d_in[11];
  const float* as2w  = (const float*)d_in[12];
  const float* ad2w  = (const float*)d_in[13];
  const float* b2    = (const float*)d_in[14];
  const float* bn2g  = (const float*)d_in[15];
  const float* bn2b  = (const float*)d_in[16];
  const float* bn2rm = (const float*)d_in[17];
  const float* bn2rv = (const float*)d_in[18];
  const float* gateW = (const float*)d_in[19];
  const float* gateB = (const float*)d_in[20];
  const float* fc1W  = (const float*)d_in[21];
  const float* fc1b  = (const float*)d_in[22];
  const float* valW  = (const float*)d_in[23];
  const float* valb  = (const float*)d_in[24];
  const float* advW  = (const float*)d_in[25];
  const float* advb  = (const float*)d_in[26];

  int N = in_sizes[0] / 32;
  int E = in_sizes[1] / 2;
  const int* esrc = eidx;
  const int* edst = eidx + E;

  int bshift = 9;
  while ((((N - 1) >> bshift) + 1) > NBUK_MAX) ++bshift;
  int nbuk = ((N - 1) >> bshift) + 1;

  float* ws = (float*)d_ws;
  size_t o = 0;
  __half* xh1h = (__half*)(ws + o); o += (size_t)N*32;   // N*64 halves
  __half* xh2h = (__half*)(ws + o); o += (size_t)N*64;   // N*128 halves
  float* as1 = ws + o; o += (size_t)N*4;
  float* ad1 = ws + o; o += (size_t)N*4;
  float* as2 = ws + o; o += (size_t)N*4;
  float* ad2 = ws + o; o += (size_t)N*4;
  float* h1  = ws + o; o += (size_t)N*64;
  float* h2  = ws + o; o += (size_t)N*128;
  float* gate = ws + o; o += (size_t)N;
  if (o & 1) ++o;
  int2* pairs = (int2*)(ws + o); o += (size_t)E*2;
  int* ib     = (int*)(ws + o);
  int* gcnt   = ib;
  int* bukcnt = ib + 512;
  int* bukcur = ib + 640;
  size_t zcnt = 768;
  int* off    = ib + zcnt;                 // N+1
  int* goff   = off + (N+1);               // NUM_G+1
  int* bukoff = goff + (NUM_G+1);          // nbuk+1
  int* csr    = bukoff + (NBUK_MAX+1);     // E

  hipMemsetAsync(gcnt, 0, zcnt*sizeof(int), stream);

  fused_hist_lin1_kernel<<<HB+BB+L1B, 256, 0, stream>>>(
      edst, E, bukcnt, bshift, nbuk, batch, gcnt,
      x, W1, as1w, ad1w, xh1h, as1, ad1, N);
  exscan2_kernel<<<2, 1024, 0, stream>>>(bukcnt, bukoff, nbuk, gcnt, goff, NUM_G);
  int nchunk = (E + CHUNK - 1) / CHUNK;
  binscat_kernel<<<nchunk, 256, 0, stream>>>(esrc, edst, E, bukoff, bukcur, pairs, bshift, nbuk);
  bucket_csr_kernel<<<nbuk, 512, 0, stream>>>(pairs, bukoff, off, csr, N, E, bshift);
  gat_agg1_kernel<<<2048, 256, 0, stream>>>(xh1h, as1, ad1, off, csr,
      b1, bn1g, bn1b, bn1rm, bn1rv, h1, N);
  lin2_kernel<<<1024, 256, 0, stream>>>(h1, W2, as2w, ad2w, xh2h, as2, ad2, N);
  gat_agg2_kernel<<<2048, 256, 0, stream>>>(xh2h, as2, ad2, off, csr,
      b2, bn2g, bn2b, bn2rm, bn2rv, gateW, gateB, h2, gate, N);
  pool_kernel<<<NUM_G, 256, 0, stream>>>(h2, gate, goff, fc1W, fc1b, valW, valb, advW, advb,
      (float*)d_out);
}

// Round 13
// 245.516 us; speedup vs baseline: 1.4755x; 1.0044x over previous
//
#include <hip/hip_runtime.h>
#include <hip/hip_fp16.h>
#include <math.h>

#define NEG_SLOPE 0.2f
#define BN_EPS_F 1e-5f
#define NUM_G 500
#define NBUK_MAX 128
#define CHUNK 4096

__device__ __forceinline__ float leaky(float x){ return x > 0.f ? x : NEG_SLOPE*x; }
__device__ __forceinline__ float bcast(float v, int k){
  return __int_as_float(__builtin_amdgcn_readlane(__float_as_int(v), k));
}

// ============ K1: fused bucket-hist + batch-hist + lin1 (role split by blockIdx) ============
#define HB 256
#define BB 64
#define L1B 512
__global__ __launch_bounds__(256) void fused_hist_lin1_kernel(
    const int* __restrict__ edst, int E, int* __restrict__ bukcnt,
    int bshift, int nbuk,
    const int* __restrict__ batch, int* __restrict__ gcnt,
    const float* __restrict__ x, const float* __restrict__ W,
    const float* __restrict__ att_s, const float* __restrict__ att_d,
    __half* __restrict__ xh, float* __restrict__ a_src, float* __restrict__ a_dst, int N)
{
  __shared__ int lhist[NUM_G];
  int t = threadIdx.x;
  int bid = blockIdx.x;
  if (bid < HB) {
    if (t < NBUK_MAX) lhist[t] = 0;
    __syncthreads();
    int i = bid*256 + t, stride = HB*256;
    for (; i < E; i += stride) atomicAdd(&lhist[edst[i] >> bshift], 1);
    __syncthreads();
    if (t < nbuk && lhist[t]) atomicAdd(&bukcnt[t], lhist[t]);
  } else if (bid < HB + BB) {
    for (int i = t; i < NUM_G; i += 256) lhist[i] = 0;
    __syncthreads();
    int i = (bid-HB)*256 + t, stride = BB*256;
    for (; i < N; i += stride) atomicAdd(&lhist[batch[i]], 1);
    __syncthreads();
    for (int i = t; i < NUM_G; i += 256) if (lhist[i]) atomicAdd(&gcnt[i], lhist[i]);
  } else {
    int lane = t & 63;
    int wid  = ((bid - HB - BB)*256 + t) >> 6;
    int nw   = (L1B*256) >> 6;
    float w[32];
    #pragma unroll
    for (int k = 0; k < 32; ++k) w[k] = W[k*64 + lane];
    float asv = att_s[lane], adv = att_d[lane];
    for (int n = wid; n < N; n += nw) {
      float xv = (lane < 32) ? x[(size_t)n*32 + lane] : 0.f;
      float acc = 0.f;
      #pragma unroll
      for (int k = 0; k < 32; ++k) acc = fmaf(bcast(xv, k), w[k], acc);
      float sv = acc*asv, dv = acc*adv;
      #pragma unroll
      for (int m = 1; m < 16; m <<= 1) { sv += __shfl_xor(sv, m); dv += __shfl_xor(dv, m); }
      xh[(size_t)n*64 + lane] = __float2half(acc);
      if ((lane & 15) == 0) { a_src[n*4 + (lane>>4)] = sv; a_dst[n*4 + (lane>>4)] = dv; }
    }
  }
}

// ============ K2: two exclusive scans in one launch ============
__global__ __launch_bounds__(1024) void exscan2_kernel(
    const int* __restrict__ in0, int* __restrict__ out0, int n0,
    const int* __restrict__ in1, int* __restrict__ out1, int n1)
{
  const int* in  = blockIdx.x ? in1  : in0;
  int*       out = blockIdx.x ? out1 : out0;
  int        n   = blockIdx.x ? n1   : n0;
  __shared__ int part[1024];
  int t = threadIdx.x;
  int per = (n + 1023) >> 10;
  int lo = t*per, hi = lo + per; if (lo > n) lo = n; if (hi > n) hi = n;
  int s = 0;
  for (int i = lo; i < hi; ++i) s += in[i];
  part[t] = s;
  __syncthreads();
  for (int ofs = 1; ofs < 1024; ofs <<= 1) {
    int v = (t >= ofs) ? part[t-ofs] : 0;
    __syncthreads();
    part[t] += v;
    __syncthreads();
  }
  int base = part[t] - s;
  for (int i = lo; i < hi; ++i) { out[i] = base; base += in[i]; }
  if (t == 1023) out[n] = part[1023];
}

// ============ K3: binned scatter ============
__global__ __launch_bounds__(256) void binscat_kernel(
    const int* __restrict__ esrc, const int* __restrict__ edst, int E,
    const int* __restrict__ bukoff, int* __restrict__ bukcur,
    int2* __restrict__ pairs, int bshift, int nbuk)
{
  __shared__ int hist[NBUK_MAX];
  __shared__ int loffs[NBUK_MAX];
  __shared__ int gbase[NBUK_MAX];
  __shared__ int2 stage[CHUNK];
  int t = threadIdx.x;
  for (int c0 = blockIdx.x*CHUNK; c0 < E; c0 += gridDim.x*CHUNK) {
    int cnt = E - c0; if (cnt > CHUNK) cnt = CHUNK;
    if (t < NBUK_MAX) hist[t] = 0;
    __syncthreads();
    for (int i = t; i < cnt; i += 256)
      atomicAdd(&hist[edst[c0+i] >> bshift], 1);
    __syncthreads();
    int cb = (t < nbuk) ? hist[t] : 0;
    for (int ofs = 1; ofs < nbuk; ofs <<= 1) {
      int v = (t < nbuk && t >= ofs) ? hist[t-ofs] : 0;
      __syncthreads();
      if (t < nbuk) hist[t] += v;
      __syncthreads();
    }
    if (t < nbuk) {
      int lo = hist[t] - cb;
      loffs[t] = lo;
      int base = atomicAdd(&bukcur[t], cb);
      gbase[t] = bukoff[t] + base - lo;
    }
    __syncthreads();
    if (t < nbuk) hist[t] = 0;
    __syncthreads();
    for (int i = t; i < cnt; i += 256) {
      int s = esrc[c0+i], d = edst[c0+i];
      int b = d >> bshift;
      int r = atomicAdd(&hist[b], 1);
      stage[loffs[b] + r] = make_int2(s, d);
    }
    __syncthreads();
    for (int j = t; j < cnt; j += 256) {
      int2 p = stage[j];
      pairs[gbase[p.y >> bshift] + j] = p;
    }
    __syncthreads();
  }
}

// ============ K4: per-bucket CSR build ============
__global__ __launch_bounds__(512) void bucket_csr_kernel(
    const int2* __restrict__ pairs, const int* __restrict__ bukoff,
    int* __restrict__ off, int* __restrict__ csr, int N, int E, int bshift)
{
  __shared__ int cnt[1024];
  __shared__ int cur[1024];
  __shared__ int part[512];
  int b = blockIdx.x, t = threadIdx.x;
  int base = b << bshift;
  int bnodes = 1 << bshift;
  int nlocal = N - base; if (nlocal > bnodes) nlocal = bnodes;
  int lo = bukoff[b], hi = bukoff[b+1];
  int gb = lo;
  for (int i = t; i < bnodes; i += 512) cnt[i] = 0;
  __syncthreads();
  for (int i = lo + t; i < hi; i += 512) atomicAdd(&cnt[pairs[i].y - base], 1);
  __syncthreads();
  int Wc = bnodes >> 9;
  int mys = 0;
  for (int j = 0; j < Wc; ++j) mys += cnt[t*Wc + j];
  part[t] = mys;
  __syncthreads();
  for (int ofs = 1; ofs < 512; ofs <<= 1) {
    int v = (t >= ofs) ? part[t-ofs] : 0;
    __syncthreads();
    part[t] += v;
    __syncthreads();
  }
  int ex = part[t] - mys;
  for (int j = 0; j < Wc; ++j) { int c = cnt[t*Wc + j]; cnt[t*Wc + j] = ex; ex += c; }
  __syncthreads();
  for (int i = t; i < nlocal; i += 512) off[base + i] = gb + cnt[i];
  if (b == 0 && t == 0) off[N] = E;
  for (int i = t; i < bnodes; i += 512) cur[i] = 0;
  __syncthreads();
  for (int i = lo + t; i < hi; i += 512) {
    int2 p = pairs[i];
    int l = p.y - base;
    int pos = gb + cnt[l] + atomicAdd(&cur[l], 1);
    csr[pos] = p.x;
  }
}

// ============ GAT agg layer 1 (F=64): csr register-staged + shuffle broadcast ============
// UNIFORM loop bounds across the wave; edge-slot validity via predicates (no divergent __shfl).
__global__ __launch_bounds__(256) void gat_agg1_kernel(
    const __half* __restrict__ xh, const float* __restrict__ a_src, const float* __restrict__ a_dst,
    const int* __restrict__ off, const int* __restrict__ csr,
    const float* __restrict__ bias, const float* __restrict__ bng, const float* __restrict__ bnb,
    const float* __restrict__ bnrm, const float* __restrict__ bnrv,
    float* __restrict__ hout, int N)
{
  int lane = threadIdx.x & 63;
  int wid  = (blockIdx.x * blockDim.x + threadIdx.x) >> 6;
  int nw   = (gridDim.x * blockDim.x) >> 6;
  int g  = lane >> 4;
  int li = lane & 15;
  int c0 = li * 4;
  int h  = li >> 2;
  float sc[4], of[4];
  #pragma unroll
  for (int j = 0; j < 4; ++j) {
    sc[j] = rsqrtf(bnrv[c0+j]+BN_EPS_F) * bng[c0+j];
    of[j] = bias[c0+j]*sc[j] + bnb[c0+j] - bnrm[c0+j]*sc[j];
  }
  for (int n = wid; n < N; n += nw) {
    int lo = off[n], hi = off[n+1];
    float adh = a_dst[n*4+h];
    float es  = __expf(leaky(a_src[n*4+h] + adh));
    float acc0=0.f, acc1=0.f, acc2=0.f, acc3=0.f, ssum=0.f;
    for (int cb = lo; cb < hi; cb += 64) {
      int cnt = hi - cb; if (cnt > 64) cnt = 64;   // wave-uniform
      int ce = cb + lane;
      int sreg = csr[ce < hi ? ce : lo];
      for (int jj = 0; jj < cnt; jj += 8) {        // wave-uniform trip count
        int j0 = jj + g, j1 = jj + 4 + g;          // j1 <= 63 always
        bool ok0 = j0 < cnt, ok1 = j1 < cnt;
        int s0 = __shfl(sreg, j0);
        int s1 = __shfl(sreg, j1);
        float a0 = a_src[s0*4+h];
        float a1 = a_src[s1*4+h];
        int2 rv0 = *(const int2*)(xh + (size_t)s0*64 + c0);
        int2 rv1 = *(const int2*)(xh + (size_t)s1*64 + c0);
        float w0 = ok0 ? __expf(leaky(a0+adh)) : 0.f;
        float w1 = ok1 ? __expf(leaky(a1+adh)) : 0.f;
        ssum += w0 + w1;
        float2 p0 = __half22float2(*(__half2*)&rv0.x);
        float2 p1 = __half22float2(*(__half2*)&rv0.y);
        float2 q0 = __half22float2(*(__half2*)&rv1.x);
        float2 q1 = __half22float2(*(__half2*)&rv1.y);
        acc0 = fmaf(w0, p0.x, acc0); acc1 = fmaf(w0, p0.y, acc1);
        acc2 = fmaf(w0, p1.x, acc2); acc3 = fmaf(w0, p1.y, acc3);
        acc0 = fmaf(w1, q0.x, acc0); acc1 = fmaf(w1, q0.y, acc1);
        acc2 = fmaf(w1, q1.x, acc2); acc3 = fmaf(w1, q1.y, acc3);
      }
    }
    #pragma unroll
    for (int m = 16; m < 64; m <<= 1) {
      acc0 += __shfl_xor(acc0, m); acc1 += __shfl_xor(acc1, m);
      acc2 += __shfl_xor(acc2, m); acc3 += __shfl_xor(acc3, m);
      ssum += __shfl_xor(ssum, m);
    }
    int2 rv = *(const int2*)(xh + (size_t)n*64 + c0);
    float2 f0 = __half22float2(*(__half2*)&rv.x);
    float2 f1 = __half22float2(*(__half2*)&rv.y);
    acc0 = fmaf(es, f0.x, acc0); acc1 = fmaf(es, f0.y, acc1);
    acc2 = fmaf(es, f1.x, acc2); acc3 = fmaf(es, f1.y, acc3);
    ssum += es;
    float inv = 1.f / (ssum + 1e-16f);
    if (g == 0) {
      float4 r;
      r.x = fmaxf(fmaf(acc0*inv, sc[0], of[0]), 0.f);
      r.y = fmaxf(fmaf(acc1*inv, sc[1], of[1]), 0.f);
      r.z = fmaxf(fmaf(acc2*inv, sc[2], of[2]), 0.f);
      r.w = fmaxf(fmaf(acc3*inv, sc[3], of[3]), 0.f);
      *(float4*)(hout + (size_t)n*64 + c0) = r;
    }
  }
}

// ============ linear 2 ============
__global__ __launch_bounds__(256) void lin2_kernel(
    const float* __restrict__ hin, const float* __restrict__ W,
    const float* __restrict__ att_s, const float* __restrict__ att_d,
    __half* __restrict__ xh, float* __restrict__ a_src, float* __restrict__ a_dst, int N)
{
  int lane = threadIdx.x & 63;
  int wid  = (blockIdx.x * blockDim.x + threadIdx.x) >> 6;
  int nw   = (gridDim.x * blockDim.x) >> 6;
  float wa[64], wb[64];
  #pragma unroll
  for (int k = 0; k < 64; ++k) { wa[k] = W[k*128 + lane]; wb[k] = W[k*128 + 64 + lane]; }
  float asa = att_s[lane], ada = att_d[lane];
  float asb = att_s[64+lane], adb = att_d[64+lane];
  for (int n = wid; n < N; n += nw) {
    float hv = hin[(size_t)n*64 + lane];
    float a0 = 0.f, a1 = 0.f;
    #pragma unroll
    for (int k = 0; k < 64; ++k) {
      float h = bcast(hv, k);
      a0 = fmaf(h, wa[k], a0); a1 = fmaf(h, wb[k], a1);
    }
    float sva = a0*asa, dva = a0*ada, svb = a1*asb, dvb = a1*adb;
    #pragma unroll
    for (int m = 1; m < 32; m <<= 1) {
      sva += __shfl_xor(sva, m); dva += __shfl_xor(dva, m);
      svb += __shfl_xor(svb, m); dvb += __shfl_xor(dvb, m);
    }
    xh[(size_t)n*128 + lane] = __float2half(a0);
    xh[(size_t)n*128 + 64 + lane] = __float2half(a1);
    if ((lane & 31) == 0) {
      int hh = lane >> 5;
      a_src[n*4 + hh] = sva;     a_dst[n*4 + hh] = dva;
      a_src[n*4 + 2 + hh] = svb; a_dst[n*4 + 2 + hh] = dvb;
    }
  }
}

// ============ GAT agg layer 2 (F=128): csr register-staged + shuffle broadcast ============
// UNIFORM loop bounds across the wave; predicated slots; no divergent __shfl.
__global__ __launch_bounds__(256) void gat_agg2_kernel(
    const __half* __restrict__ xh, const float* __restrict__ a_src, const float* __restrict__ a_dst,
    const int* __restrict__ off, const int* __restrict__ csr,
    const float* __restrict__ bias, const float* __restrict__ bng, const float* __restrict__ bnb,
    const float* __restrict__ bnrm, const float* __restrict__ bnrv,
    const float* __restrict__ gateW, const float* __restrict__ gateB,
    float* __restrict__ hout, float* __restrict__ gate, int N)
{
  int lane = threadIdx.x & 63;
  int wid  = (blockIdx.x * blockDim.x + threadIdx.x) >> 6;
  int nw   = (gridDim.x * blockDim.x) >> 6;
  int g  = lane >> 4;        // edge slot 0..3
  int li = lane & 15;        // 16 lanes per edge
  int c0 = li * 8;           // channels c0..c0+7
  int h  = li >> 2;          // head = c0>>5
  float sc[8], of[8], gw[8];
  #pragma unroll
  for (int j = 0; j < 8; ++j) {
    sc[j] = rsqrtf(bnrv[c0+j]+BN_EPS_F) * bng[c0+j];
    of[j] = bias[c0+j]*sc[j] + bnb[c0+j] - bnrm[c0+j]*sc[j];
    gw[j] = gateW[c0+j];
  }
  float gb = gateB[0];
  for (int n = wid; n < N; n += nw) {
    int lo = off[n], hi = off[n+1];
    float adh = a_dst[n*4+h];
    float es  = __expf(leaky(a_src[n*4+h] + adh));
    float acc0=0.f, acc1=0.f, acc2=0.f, acc3=0.f;
    float acc4=0.f, acc5=0.f, acc6=0.f, acc7=0.f, ssum=0.f;
    for (int cb = lo; cb < hi; cb += 64) {
      int cnt = hi - cb; if (cnt > 64) cnt = 64;   // wave-uniform
      int ce = cb + lane;
      int sreg = csr[ce < hi ? ce : lo];
      for (int jj = 0; jj < cnt; jj += 8) {        // wave-uniform trip count
        int j0 = jj + g, j1 = jj + 4 + g;          // j1 <= 63 always
        bool ok0 = j0 < cnt, ok1 = j1 < cnt;
        int s0 = __shfl(sreg, j0);
        int s1 = __shfl(sreg, j1);
        float a0 = a_src[s0*4+h];
        float a1 = a_src[s1*4+h];
        int4 rv0 = *(const int4*)(xh + (size_t)s0*128 + c0);
        int4 rv1 = *(const int4*)(xh + (size_t)s1*128 + c0);
        float w0 = ok0 ? __expf(leaky(a0+adh)) : 0.f;
        float w1 = ok1 ? __expf(leaky(a1+adh)) : 0.f;
        ssum += w0 + w1;
        float2 p0 = __half22float2(*(__half2*)&rv0.x);
        float2 p1 = __half22float2(*(__half2*)&rv0.y);
        float2 p2 = __half22float2(*(__half2*)&rv0.z);
        float2 p3 = __half22float2(*(__half2*)&rv0.w);
        acc0 = fmaf(w0, p0.x, acc0); acc1 = fmaf(w0, p0.y, acc1);
        acc2 = fmaf(w0, p1.x, acc2); acc3 = fmaf(w0, p1.y, acc3);
        acc4 = fmaf(w0, p2.x, acc4); acc5 = fmaf(w0, p2.y, acc5);
        acc6 = fmaf(w0, p3.x, acc6); acc7 = fmaf(w0, p3.y, acc7);
        float2 q0 = __half22float2(*(__half2*)&rv1.x);
        float2 q1 = __half22float2(*(__half2*)&rv1.y);
        float2 q2 = __half22float2(*(__half2*)&rv1.z);
        float2 q3 = __half22float2(*(__half2*)&rv1.w);
        acc0 = fmaf(w1, q0.x, acc0); acc1 = fmaf(w1, q0.y, acc1);
        acc2 = fmaf(w1, q1.x, acc2); acc3 = fmaf(w1, q1.y, acc3);
        acc4 = fmaf(w1, q2.x, acc4); acc5 = fmaf(w1, q2.y, acc5);
        acc6 = fmaf(w1, q3.x, acc6); acc7 = fmaf(w1, q3.y, acc7);
      }
    }
    #pragma unroll
    for (int m = 16; m < 64; m <<= 1) {
      acc0 += __shfl_xor(acc0, m); acc1 += __shfl_xor(acc1, m);
      acc2 += __shfl_xor(acc2, m); acc3 += __shfl_xor(acc3, m);
      acc4 += __shfl_xor(acc4, m); acc5 += __shfl_xor(acc5, m);
      acc6 += __shfl_xor(acc6, m); acc7 += __shfl_xor(acc7, m);
      ssum += __shfl_xor(ssum, m);
    }
    // self loop
    int4 rv = *(const int4*)(xh + (size_t)n*128 + c0);
    float2 f0 = __half22float2(*(__half2*)&rv.x);
    float2 f1 = __half22float2(*(__half2*)&rv.y);
    float2 f2 = __half22float2(*(__half2*)&rv.z);
    float2 f3 = __half22float2(*(__half2*)&rv.w);
    acc0 = fmaf(es, f0.x, acc0); acc1 = fmaf(es, f0.y, acc1);
    acc2 = fmaf(es, f1.x, acc2); acc3 = fmaf(es, f1.y, acc3);
    acc4 = fmaf(es, f2.x, acc4); acc5 = fmaf(es, f2.y, acc5);
    acc6 = fmaf(es, f3.x, acc6); acc7 = fmaf(es, f3.y, acc7);
    ssum += es;
    float inv = 1.f / (ssum + 1e-16f);
    float r0 = fmaxf(fmaf(acc0*inv, sc[0], of[0]), 0.f);
    float r1 = fmaxf(fmaf(acc1*inv, sc[1], of[1]), 0.f);
    float r2 = fmaxf(fmaf(acc2*inv, sc[2], of[2]), 0.f);
    float r3 = fmaxf(fmaf(acc3*inv, sc[3], of[3]), 0.f);
    float r4 = fmaxf(fmaf(acc4*inv, sc[4], of[4]), 0.f);
    float r5 = fmaxf(fmaf(acc5*inv, sc[5], of[5]), 0.f);
    float r6 = fmaxf(fmaf(acc6*inv, sc[6], of[6]), 0.f);
    float r7 = fmaxf(fmaf(acc7*inv, sc[7], of[7]), 0.f);
    if (g == 0) {
      float4 w0 = make_float4(r0, r1, r2, r3);
      float4 w1 = make_float4(r4, r5, r6, r7);
      *(float4*)(hout + (size_t)n*128 + c0)     = w0;
      *(float4*)(hout + (size_t)n*128 + c0 + 4) = w1;
    }
    float gl = r0*gw[0] + r1*gw[1] + r2*gw[2] + r3*gw[3]
             + r4*gw[4] + r5*gw[5] + r6*gw[6] + r7*gw[7];
    #pragma unroll
    for (int m = 1; m < 16; m <<= 1) gl += __shfl_xor(gl, m);
    if (lane == 0) gate[n] = gl + gb;
  }
}

// ============ per-graph attention pooling + MLP heads (256 threads, 2x node parallel) ========
__global__ __launch_bounds__(256) void pool_kernel(
    const float* __restrict__ h2, const float* __restrict__ gate, const int* __restrict__ goff,
    const float* __restrict__ fc1W, const float* __restrict__ fc1b,
    const float* __restrict__ valW, const float* __restrict__ valb,
    const float* __restrict__ advW, const float* __restrict__ advb,
    float* __restrict__ out)
{
  int g = blockIdx.x, t = threadIdx.x;
  int lo = goff[g], hi = goff[g+1];
  __shared__ float red[4];
  __shared__ float pld2[2][128];
  __shared__ float pld[128];
  __shared__ float zs[32];
  __shared__ float sval;
  __shared__ float adv_s[16];

  float m = -3.4e38f;
  for (int n = lo+t; n < hi; n += 256) m = fmaxf(m, gate[n]);
  #pragma unroll
  for (int msk = 1; msk < 64; msk <<= 1) m = fmaxf(m, __shfl_xor(m, msk));
  if ((t & 63) == 0) red[t >> 6] = m;
  __syncthreads();
  m = fmaxf(fmaxf(red[0], red[1]), fmaxf(red[2], red[3]));
  __syncthreads();
  float sl = 0.f;
  for (int n = lo+t; n < hi; n += 256) sl += __expf(gate[n]-m);
  #pragma unroll
  for (int msk = 1; msk < 64; msk <<= 1) sl += __shfl_xor(sl, msk);
  if ((t & 63) == 0) red[t >> 6] = sl;
  __syncthreads();
  float s = red[0] + red[1] + red[2] + red[3];
  int f = t & 127, p = t >> 7;
  float acc = 0.f;
  for (int n = lo + p; n < hi; n += 2) {
    float w = __expf(gate[n]-m);
    acc += w * h2[(size_t)n*128 + f];
  }
  pld2[p][f] = acc;
  __syncthreads();
  if (t < 128) pld[t] = (pld2[0][t] + pld2[1][t]) / (s + 1e-16f);
  __syncthreads();
  if (t < 32) {
    float z = fc1b[t];
    #pragma unroll 4
    for (int k = 0; k < 128; ++k) z += pld[k]*fc1W[k*32 + t];
    zs[t] = fmaxf(z, 0.f);
  }
  __syncthreads();
  if (t < 32) {
    float pv = zs[t]*valW[t];
    #pragma unroll
    for (int msk = 1; msk < 32; msk <<= 1) pv += __shfl_xor(pv, msk);
    if (t == 0) sval = pv + valb[0];
  }
  if (t < 16) {
    float a = advb[t];
    #pragma unroll
    for (int k = 0; k < 32; ++k) a += zs[k]*advW[k*16 + t];
    adv_s[t] = a;
  }
  __syncthreads();
  if (t < 16) {
    float amean = adv_s[t];
    #pragma unroll
    for (int msk = 1; msk < 16; msk <<= 1) amean += __shfl_xor(amean, msk);
    amean *= (1.f/16.f);
    out[g*16 + t] = sval + adv_s[t] - amean;
  }
}

extern "C" void kernel_launch(void* const* d_in, const int* in_sizes, int n_in,
                              void* d_out, int out_size, void* d_ws, size_t ws_size,
                              hipStream_t stream)
{
  const float* x     = (const float*)d_in[0];
  const int*   eidx  = (const int*)  d_in[1];
  const int*   batch = (const int*)  d_in[2];
  const float* W1    = (const float*)d_in[3];
  const float* as1w  = (const float*)d_in[4];
  const float* ad1w  = (const float*)d_in[5];
  const float* b1    = (const float*)d_in[6];
  const float* bn1g  = (const float*)d_in[7];
  const float* bn1b  = (const float*)d_in[8];
  const float* bn1rm = (const float*)d_in[9];
  const float* bn1rv = (const float*)d_in[10];
  const float* W2    = (const float*)d_in[11];
  const float* as2w  = (const float*)d_in[12];
  const float* ad2w  = (const float*)d_in[13];
  const float* b2    = (const float*)d_in[14];
  const float* bn2g  = (const float*)d_in[15];
  const float* bn2b  = (const float*)d_in[16];
  const float* bn2rm = (const float*)d_in[17];
  const float* bn2rv = (const float*)d_in[18];
  const float* gateW = (const float*)d_in[19];
  const float* gateB = (const float*)d_in[20];
  const float* fc1W  = (const float*)d_in[21];
  const float* fc1b  = (const float*)d_in[22];
  const float* valW  = (const float*)d_in[23];
  const float* valb  = (const float*)d_in[24];
  const float* advW  = (const float*)d_in[25];
  const float* advb  = (const float*)d_in[26];

  int N = in_sizes[0] / 32;
  int E = in_sizes[1] / 2;
  const int* esrc = eidx;
  const int* edst = eidx + E;

  int bshift = 9;
  while ((((N - 1) >> bshift) + 1) > NBUK_MAX) ++bshift;
  int nbuk = ((N - 1) >> bshift) + 1;

  float* ws = (float*)d_ws;
  size_t o = 0;
  __half* xh1h = (__half*)(ws + o); o += (size_t)N*32;   // N*64 halves
  __half* xh2h = (__half*)(ws + o); o += (size_t)N*64;   // N*128 halves
  float* as1 = ws + o; o += (size_t)N*4;
  float* ad1 = ws + o; o += (size_t)N*4;
  float* as2 = ws + o; o += (size_t)N*4;
  float* ad2 = ws + o; o += (size_t)N*4;
  float* h1  = ws + o; o += (size_t)N*64;
  float* h2  = ws + o; o += (size_t)N*128;
  float* gate = ws + o; o += (size_t)N;
  if (o & 1) ++o;
  int2* pairs = (int2*)(ws + o); o += (size_t)E*2;
  int* ib     = (int*)(ws + o);
  int* gcnt   = ib;
  int* bukcnt = ib + 512;
  int* bukcur = ib + 640;
  size_t zcnt = 768;
  int* off    = ib + zcnt;                 // N+1
  int* goff   = off + (N+1);               // NUM_G+1
  int* bukoff = goff + (NUM_G+1);          // nbuk+1
  int* csr    = bukoff + (NBUK_MAX+1);     // E

  hipMemsetAsync(gcnt, 0, zcnt*sizeof(int), stream);

  fused_hist_lin1_kernel<<<HB+BB+L1B, 256, 0, stream>>>(
      edst, E, bukcnt, bshift, nbuk, batch, gcnt,
      x, W1, as1w, ad1w, xh1h, as1, ad1, N);
  exscan2_kernel<<<2, 1024, 0, stream>>>(bukcnt, bukoff, nbuk, gcnt, goff, NUM_G);
  int nchunk = (E + CHUNK - 1) / CHUNK;
  binscat_kernel<<<nchunk, 256, 0, stream>>>(esrc, edst, E, bukoff, bukcur, pairs, bshift, nbuk);
  bucket_csr_kernel<<<nbuk, 512, 0, stream>>>(pairs, bukoff, off, csr, N, E, bshift);
  gat_agg1_kernel<<<2048, 256, 0, stream>>>(xh1h, as1, ad1, off, csr,
      b1, bn1g, bn1b, bn1rm, bn1rv, h1, N);
  lin2_kernel<<<1024, 256, 0, stream>>>(h1, W2, as2w, ad2w, xh2h, as2, ad2, N);
  gat_agg2_kernel<<<2048, 256, 0, stream>>>(xh2h, as2, ad2, off, csr,
      b2, bn2g, bn2b, bn2rm, bn2rv, gateW, gateB, h2, gate, N);
  pool_kernel<<<NUM_G, 256, 0, stream>>>(h2, gate, goff, fc1W, fc1b, valW, valb, advW, advb,
      (float*)d_out);
}